// Round 6
// baseline (348.559 us; speedup 1.0000x reference)
//
#include <hip/hip_runtime.h>
#include <stdint.h>

#define DIMN 1024
#define NH 16
#define HD 64
#define FFN 4096
#define BBATCH 2
#define SSEQ 2048
#define MROWS (BBATCH*SSEQ)   // 4096

typedef __bf16 bf16;
typedef __bf16 bf16x8 __attribute__((ext_vector_type(8)));
typedef __bf16 bf16x4 __attribute__((ext_vector_type(4)));
typedef float f32x4 __attribute__((ext_vector_type(4)));
typedef float f32x16 __attribute__((ext_vector_type(16)));
typedef uint32_t u32x4 __attribute__((ext_vector_type(4)));

#define AS1 __attribute__((address_space(1)))
#define AS3 __attribute__((address_space(3)))

__device__ __forceinline__ void gload16(const bf16* g, bf16* l) {
  __builtin_amdgcn_global_load_lds((AS1 const void*)g, (AS3 void*)l, 16, 0, 0);
}

__device__ __forceinline__ uint32_t pkbf(float a, float b) {
  union { bf16 h[2]; uint32_t u; } x;
  x.h[0] = (bf16)a; x.h[1] = (bf16)b;
  return x.u;
}

// ---------------- rope table: tab[s*64 + d] = cos, tab[s*64+32+d] = sin ----
__global__ void rope_table_kernel(float* __restrict__ tab) {
  int i = blockIdx.x * blockDim.x + threadIdx.x;   // 0..65535
  int s = i >> 5, d = i & 31;
  float invf = exp2f(-(float)d * 0.4152410118609203f);
  float fr = (float)s * invf;
  tab[s*64 + d]      = cosf(fr);
  tab[s*64 + 32 + d] = sinf(fr);
}

// ---------------- f32 -> bf16 cast (vector x4) -----------------------------
__global__ void cast_f32_bf16(const float* __restrict__ in, bf16* __restrict__ out, int n4) {
  int i = blockIdx.x * blockDim.x + threadIdx.x;
  if (i < n4) {
    f32x4 v = ((const f32x4*)in)[i];
    bf16x4 o = {(bf16)v.x, (bf16)v.y, (bf16)v.z, (bf16)v.w};
    ((bf16x4*)out)[i] = o;
  }
}

// ---------------- transpose + cast: f32 [R][C] -> bf16 [C][R] --------------
__global__ __launch_bounds__(256) void transpose_cast_f32_bf16(
    const float* __restrict__ in, bf16* __restrict__ out, int R, int C) {
  __shared__ float t[32][33];
  int bx = blockIdx.x, by = blockIdx.y;
  int x = threadIdx.x, y = threadIdx.y;     // (32, 8)
  #pragma unroll
  for (int j = 0; j < 4; ++j) {
    int r = by*32 + y*4 + j;
    t[y*4+j][x] = in[(size_t)r*C + bx*32 + x];
  }
  __syncthreads();
  #pragma unroll
  for (int j = 0; j < 4; ++j) {
    int c = bx*32 + y*4 + j;
    out[(size_t)c*R + by*32 + x] = (bf16)t[x][y*4+j];
  }
}

// ---------------- RMSNorm over (sum of NP partials + resid) ----------------
template<int NP>
__global__ __launch_bounds__(256) void rmsnorm_sum_kernel(
    const float* __restrict__ parts, const float* __restrict__ resid,
    const float* __restrict__ sc,
    float* __restrict__ outf, bf16* __restrict__ outb) {
  int row = blockIdx.x;
  int tid = threadIdx.x;
  size_t off = (size_t)row * DIMN;
  f32x4 v = ((const f32x4*)(resid + off))[tid];
  #pragma unroll
  for (int p = 0; p < NP; ++p) {
    f32x4 a = ((const f32x4*)(parts + (size_t)p * MROWS * DIMN + off))[tid];
    v.x += a.x; v.y += a.y; v.z += a.z; v.w += a.w;
  }
  float ss = v.x*v.x + v.y*v.y + v.z*v.z + v.w*v.w;
  #pragma unroll
  for (int m = 1; m < 64; m <<= 1) ss += __shfl_xor(ss, m);
  __shared__ float red[4];
  if ((tid & 63) == 0) red[tid >> 6] = ss;
  __syncthreads();
  float tot = red[0] + red[1] + red[2] + red[3];
  float inv = 1.f / (sqrtf(tot) * 0.03125f + 1e-8f);
  f32x4 s4 = ((const f32x4*)sc)[tid];
  f32x4 o = {v.x*s4.x*inv, v.y*s4.y*inv, v.z*s4.z*inv, v.w*s4.w*inv};
  if (outf) ((f32x4*)(outf + off))[tid] = o;
  if (outb) {
    bf16x4 ob = {(bf16)o.x, (bf16)o.y, (bf16)o.z, (bf16)o.w};
    ((bf16x4*)(outb + off))[tid] = ob;
  }
}

// ---------------- GEMM engine 1: 128x128 tile, 4 waves ---------------------
// EPI 0: QKV+rope -> fragment-layout Q/K/V (Q pre-scaled by 0.125*log2e)
// EPI 4: f32 partial: o0[z*M*N + r*N + c] = acc   (split-K)
template<int EPI>
__global__ void __launch_bounds__(256, 2) gemm_bt(
    const bf16* __restrict__ A, const bf16* __restrict__ B,
    int M, int N, int K,
    void* __restrict__ o0, void* __restrict__ o1, void* __restrict__ o2,
    const void* __restrict__ a0, const void* __restrict__ a1) {
  __shared__ __align__(16) bf16 sh_a[2*4096];
  __shared__ __align__(16) bf16 sh_b[2*4096];
  const int tid  = threadIdx.x;
  const int lane = tid & 63;
  const int wid  = tid >> 6;

  int gx  = gridDim.x;
  int bid = blockIdx.y * gx + blockIdx.x;
  int nwg = gx * gridDim.y;
  int cpx = nwg >> 3;
  int swz = (bid & 7) * cpx + (bid >> 3);
  int bxi = swz % gx, byi = swz / gx;

  const int m0 = byi * 128, n0 = bxi * 128;
  const int wm = (wid >> 1) * 64, wn = (wid & 1) * 64;

  const int kb = blockIdx.z;
  const int KC = K / (int)gridDim.z;

  f32x4 acc[4][4] = {};

  const bf16* a_base = A + (size_t)m0 * K + (size_t)kb * KC;
  const bf16* b_base = B + (size_t)n0 * K + (size_t)kb * KC;

  auto stage = [&](int kt, int buf) {
    const int lb = buf * 4096;
    #pragma unroll
    for (int i = 0; i < 2; ++i) {
      int idx = i*256 + tid;
      size_t go = (size_t)(idx >> 2)*K + (size_t)kt*32 + (idx & 3)*8;
      gload16(a_base + go, &sh_a[lb + idx*8]);
    }
    #pragma unroll
    for (int i = 0; i < 2; ++i) {
      int idx = i*256 + tid;
      size_t go = (size_t)(idx >> 2)*K + (size_t)kt*32 + (idx & 3)*8;
      gload16(b_base + go, &sh_b[lb + idx*8]);
    }
  };

  const int nsteps = KC >> 5;
  stage(0, 0);
  for (int t = 0; t < nsteps; ++t) {
    const int cb = t & 1;
    if (t + 1 < nsteps) {
      stage(t+1, cb ^ 1);
      asm volatile("s_waitcnt vmcnt(4)" ::: "memory");
    } else {
      asm volatile("s_waitcnt vmcnt(0)" ::: "memory");
    }
    __builtin_amdgcn_sched_barrier(0);
    __builtin_amdgcn_s_barrier();
    __builtin_amdgcn_sched_barrier(0);

    const int lb = cb * 4096;
    bf16x8 af[4], bfr[4];
    #pragma unroll
    for (int m = 0; m < 4; ++m)
      af[m] = *(const bf16x8*)&sh_a[lb + (wm + m*16 + (lane & 15))*32 + (lane >> 4)*8];
    #pragma unroll
    for (int n = 0; n < 4; ++n)
      bfr[n] = *(const bf16x8*)&sh_b[lb + (wn + n*16 + (lane & 15))*32 + (lane >> 4)*8];
    __builtin_amdgcn_s_setprio(1);
    #pragma unroll
    for (int m = 0; m < 4; ++m)
      #pragma unroll
      for (int n = 0; n < 4; ++n)
        acc[m][n] = __builtin_amdgcn_mfma_f32_16x16x32_bf16(af[m], bfr[n], acc[m][n], 0, 0, 0);
    __builtin_amdgcn_s_setprio(0);
    __builtin_amdgcn_sched_barrier(0);
    __builtin_amdgcn_s_barrier();
  }

  const int rq = (lane >> 4) * 4;
  const int cl = lane & 15;

  if constexpr (EPI == 0) {
    bf16* q_p = (bf16*)o0; bf16* k_p = (bf16*)o1; bf16* v_p = (bf16*)o2;
    const float* rope = (const float*)a0;
    int sec = (n0 + wn) >> 10;             // 0=q, 1=k, 2=v
    int h   = ((n0 + wn) & 1023) >> 6;
    const float qsc = (sec == 0) ? 0.18033688011112042f : 1.0f;  // 0.125*log2(e)
    #pragma unroll
    for (int m = 0; m < 4; ++m) {
      #pragma unroll
      for (int reg = 0; reg < 4; ++reg) {
        int r  = m0 + wm + m*16 + rq + reg;
        int b_ = r >> 11, s_ = r & 2047;
        int tile = s_ >> 5;
        size_t tb = ((size_t)(b_*NH + h) * 64 + tile) * 2048;  // 4KB tile base
        if (sec == 2) {
          int kvl = s_ & 31;
          int ks = kvl >> 4, hiv = (kvl >> 3) & 1, jv = kvl & 7;
          #pragma unroll
          for (int n = 0; n < 4; ++n) {
            int half = n >> 1;
            int qlv  = (n & 1) * 16 + cl;
            v_p[tb + (size_t)(ks*2 + half)*512 + (hiv*32 + qlv)*8 + jv] =
                (bf16)acc[m][n][reg];
          }
        } else {
          int qlt = s_ & 31;
          bf16* dst = (sec == 0 ? q_p : k_p);
          int lo = ((cl >> 3) * 32 + qlt) * 8 + (cl & 7);
          #pragma unroll
          for (int n = 0; n < 2; ++n) {
            int d1 = n*16 + cl;
            float c1 = rope[s_*64 + d1];
            float s1 = rope[s_*64 + 32 + d1];
            float x1 = acc[m][n][reg], x2 = acc[m][n+2][reg];
            dst[tb + (size_t)n*512 + lo]       = (bf16)((x1*c1 - x2*s1) * qsc);
            dst[tb + (size_t)(n+2)*512 + lo]   = (bf16)((x1*s1 + x2*c1) * qsc);
          }
        }
      }
    }
  } else if constexpr (EPI == 4) {
    float* op = (float*)o0 + (size_t)kb * M * N;
    #pragma unroll
    for (int m = 0; m < 4; ++m)
      #pragma unroll
      for (int n = 0; n < 4; ++n)
        #pragma unroll
        for (int reg = 0; reg < 4; ++reg) {
          int r = m0 + wm + m*16 + rq + reg;
          int c = n0 + wn + n*16 + cl;
          op[(size_t)r*N + c] = acc[m][n][reg];
        }
  }
}

// ---------------- GEMM engine 2 (fused FFN1 only) --------------------------
// BM=256, BN=128 per matrix, BK=32, 8 waves (512 thr), wave tile 128x32
// per matrix. A: LDS 4-slot ring (64 KB), 3-tile prefetch, XOR-swizzled
// (linear gload_lds dest + inverse-permuted global source chunk + swizzled
// read -> 8-way conflict becomes 4-way). B/C (gate/lin weights): per-wave
// PRIVATE columns -> loaded global->reg directly, 1-tile register dbuf.
// vmcnt: per iter issues A(t+3)[2] then BC(t+1)[8]; ops newer than BC(t)
// = 10 -> vmcnt(10) steady, 8 when A staging done, 0 on last iter.
__global__ void __launch_bounds__(512, 2) gemm256_ffn1(
    const bf16* __restrict__ A, const bf16* __restrict__ Bg,
    const bf16* __restrict__ Bl, int M, int N, int K,
    bf16* __restrict__ o0, const float* __restrict__ bgv,
    const float* __restrict__ blv) {
  __shared__ __align__(16) bf16 shA[4][256*32];   // 64 KB ring
  const int tid  = threadIdx.x;
  const int lane = tid & 63;
  const int wid  = tid >> 6;       // 0..7
  const int wr   = wid >> 2;       // 0..1  (row half)
  const int wc   = wid & 3;        // 0..3  (col quarter)

  int gx  = gridDim.x;
  int bid = blockIdx.y * gx + blockIdx.x;
  int nwg = gx * gridDim.y;
  int cpx = nwg >> 3;
  int swz = (bid & 7) * cpx + (bid >> 3);
  int bxi = swz % gx, byi = swz / gx;
  const int m0 = byi * 256, n0 = bxi * 128;

  const int nt = K >> 5;

  const bf16* a_base  = A  + (size_t)m0 * K;
  const bf16* bg_base = Bg + (size_t)(n0 + wc*32) * K;
  const bf16* bl_base = Bl + (size_t)(n0 + wc*32) * K;

  const int fr = lane & 15, fq = lane >> 4;

  // --- A staging (swizzled): thread covers rows srow, 128+srow; nominal
  // slot snom; fetches global chunk sgl = snom ^ (row&3) (row&3 == srow&3).
  const int srow = tid >> 2;
  const int snom = tid & 3;
  const int sgl  = snom ^ (srow & 3);
  auto stA = [&](int kt, int s) {
    #pragma unroll
    for (int c = 0; c < 2; ++c) {
      int row = c*128 + srow;
      gload16(a_base + (size_t)row*K + (size_t)kt*32 + sgl*8,
              &shA[s][row*32 + snom*8]);
    }
  };
  // --- B/C register loads: frag n covers col n*16+fr, k-off fq*8
  auto ldBC = [&](int kt, bf16x8* bb, bf16x8* cc) {
    #pragma unroll
    for (int n = 0; n < 2; ++n) {
      bb[n] = *(const bf16x8*)(bg_base + (size_t)(n*16 + fr)*K + (size_t)kt*32 + fq*8);
      cc[n] = *(const bf16x8*)(bl_base + (size_t)(n*16 + fr)*K + (size_t)kt*32 + fq*8);
    }
  };

  f32x4 acc [8][2] = {};
  f32x4 acc2[8][2] = {};
  bf16x8 bcur[2], ccur[2], bnxt[2], cnxt[2];

  // prologue: A tiles 0..2, BC tile 0
  stA(0, 0); stA(1, 1); stA(2, 2);
  ldBC(0, bcur, ccur);

  const int aslot = (fq ^ (fr & 3)) * 8;   // swizzled 16B slot for A reads

  for (int t = 0; t < nt; ++t) {
    const int s = t & 3;
    if (t + 3 < nt) stA(t+3, (t+3) & 3);
    if (t + 1 < nt) ldBC(t+1, bnxt, cnxt);
    if (t + 3 < nt)      asm volatile("s_waitcnt vmcnt(10)" ::: "memory");
    else if (t + 1 < nt) asm volatile("s_waitcnt vmcnt(8)" ::: "memory");
    else                 asm volatile("s_waitcnt vmcnt(0)" ::: "memory");
    __builtin_amdgcn_sched_barrier(0);
    __builtin_amdgcn_s_barrier();          // A tile t visible to all waves
    __builtin_amdgcn_sched_barrier(0);

    // sub-phase 0: m-frags 0..3
    {
      bf16x8 af[4];
      #pragma unroll
      for (int m = 0; m < 4; ++m)
        af[m] = *(const bf16x8*)&shA[s][(wr*128 + m*16 + fr)*32 + aslot];
      __builtin_amdgcn_s_setprio(1);
      #pragma unroll
      for (int m = 0; m < 4; ++m)
        #pragma unroll
        for (int n = 0; n < 2; ++n) {
          acc [m][n] = __builtin_amdgcn_mfma_f32_16x16x32_bf16(af[m], bcur[n], acc [m][n], 0, 0, 0);
          acc2[m][n] = __builtin_amdgcn_mfma_f32_16x16x32_bf16(af[m], ccur[n], acc2[m][n], 0, 0, 0);
        }
      __builtin_amdgcn_s_setprio(0);
    }
    // sub-phase 1: m-frags 4..7
    {
      bf16x8 af[4];
      #pragma unroll
      for (int m = 0; m < 4; ++m)
        af[m] = *(const bf16x8*)&shA[s][(wr*128 + (m+4)*16 + fr)*32 + aslot];
      __builtin_amdgcn_s_setprio(1);
      #pragma unroll
      for (int m = 0; m < 4; ++m)
        #pragma unroll
        for (int n = 0; n < 2; ++n) {
          acc [m+4][n] = __builtin_amdgcn_mfma_f32_16x16x32_bf16(af[m], bcur[n], acc [m+4][n], 0, 0, 0);
          acc2[m+4][n] = __builtin_amdgcn_mfma_f32_16x16x32_bf16(af[m], ccur[n], acc2[m+4][n], 0, 0, 0);
        }
      __builtin_amdgcn_s_setprio(0);
    }
    __builtin_amdgcn_sched_barrier(0);
    __builtin_amdgcn_s_barrier();          // all waves done reading slot s
    // rotate BC register buffers (static indexing, rule #20)
    #pragma unroll
    for (int n = 0; n < 2; ++n) { bcur[n] = bnxt[n]; ccur[n] = cnxt[n]; }
  }

  const int rq = (lane >> 4) * 4;
  const int cl = lane & 15;
  #pragma unroll
  for (int m = 0; m < 8; ++m)
    #pragma unroll
    for (int n = 0; n < 2; ++n)
      #pragma unroll
      for (int reg = 0; reg < 4; ++reg) {
        int r = m0 + wr*128 + m*16 + rq + reg;
        int c = n0 + wc*32 + n*16 + cl;
        float gv = acc [m][n][reg] + bgv[c];
        float lv = acc2[m][n][reg] + blv[c];
        float sg = 1.f / (1.f + __expf(-gv));
        o0[(size_t)r*N + c] = (bf16)(sg * lv);
      }
}

// ---------------- fused attention (no-max softmax, fragment-layout inputs) -
__global__ void __launch_bounds__(256) attn_kernel(
    const bf16* __restrict__ qf_g, const bf16* __restrict__ kf_g,
    const bf16* __restrict__ vf_g, bf16* __restrict__ ao_g) {
  __shared__ __align__(16) bf16 lds_k[2*2048];
  __shared__ __align__(16) bf16 lds_v[2*2048];
  const int tid  = threadIdx.x;
  const int lane = tid & 63;
  const int qw   = tid >> 6;      // wave's 32-row q group (0..3)
  const int hi   = lane >> 5;
  const int ql   = lane & 31;
  const int bh   = blockIdx.y;
  const int b_   = bh >> 4, h = bh & 15;
  const int q0   = blockIdx.x * 128 + qw * 32;
  const int qt   = blockIdx.x * 4 + qw;

  const bf16* qtile = qf_g + ((size_t)bh*64 + qt) * 2048;
  const bf16* kbase = kf_g + (size_t)bh * 64 * 2048;
  const bf16* vbase = vf_g + (size_t)bh * 64 * 2048;

  bf16x8 qf[4];
  #pragma unroll
  for (int ds = 0; ds < 4; ++ds)
    qf[ds] = *(const bf16x8*)&qtile[ds*512 + lane*8];

  f32x16 o0 = {}, o1 = {};
  float lrun = 0.f;

  gload16(kbase + tid*8, &lds_k[tid*8]);
  gload16(vbase + tid*8, &lds_v[tid*8]);

  for (int t = 0; t < 64; ++t) {
    const int cur = (t & 1) * 2048;
    if (t < 63) {
      const int nxt = 2048 - cur;
      gload16(kbase + (size_t)(t+1)*2048 + tid*8, &lds_k[nxt + tid*8]);
      gload16(vbase + (size_t)(t+1)*2048 + tid*8, &lds_v[nxt + tid*8]);
      asm volatile("s_waitcnt vmcnt(2)" ::: "memory");
    } else {
      asm volatile("s_waitcnt vmcnt(0)" ::: "memory");
    }
    __builtin_amdgcn_sched_barrier(0);
    __builtin_amdgcn_s_barrier();
    __builtin_amdgcn_sched_barrier(0);

    f32x16 st = {};
    __builtin_amdgcn_s_setprio(1);
    #pragma unroll
    for (int ds = 0; ds < 4; ++ds) {
      bf16x8 kf = *(const bf16x8*)&lds_k[cur + ds*512 + lane*8];
      st = __builtin_amdgcn_mfma_f32_32x32x16_bf16(kf, qf[ds], st, 0, 0, 0);
    }
    __builtin_amdgcn_s_setprio(0);
    float p[16];
    float psum = 0.f;
    #pragma unroll
    for (int r = 0; r < 16; ++r) { p[r] = __builtin_amdgcn_exp2f(st[r]); psum += p[r]; }
    lrun += psum;

    uint32_t w0 = pkbf(p[0],p[1]),   w1 = pkbf(p[2],p[3]);
    uint32_t w2 = pkbf(p[4],p[5]),   w3 = pkbf(p[6],p[7]);
    uint32_t w4 = pkbf(p[8],p[9]),   w5 = pkbf(p[10],p[11]);
    uint32_t w6 = pkbf(p[12],p[13]), w7 = pkbf(p[14],p[15]);
    asm("v_permlane32_swap_b32 %0, %1" : "+v"(w0), "+v"(w2));
    asm("v_permlane32_swap_b32 %0, %1" : "+v"(w1), "+v"(w3));
    asm("v_permlane32_swap_b32 %0, %1" : "+v"(w4), "+v"(w6));
    asm("v_permlane32_swap_b32 %0, %1" : "+v"(w5), "+v"(w7));

    __builtin_amdgcn_s_setprio(1);
    {
      union { u32x4 u; bf16x8 b; } pu;
      u32x4 pwa = {w0, w1, w2, w3};
      pu.u = pwa;
      bf16x8 v0 = *(const bf16x8*)&lds_v[cur + 0*512 + lane*8];
      bf16x8 v1 = *(const bf16x8*)&lds_v[cur + 1*512 + lane*8];
      o0 = __builtin_amdgcn_mfma_f32_32x32x16_bf16(v0, pu.b, o0, 0, 0, 0);
      o1 = __builtin_amdgcn_mfma_f32_32x32x16_bf16(v1, pu.b, o1, 0, 0, 0);
      u32x4 pwb = {w4, w5, w6, w7};
      pu.u = pwb;
      bf16x8 v2 = *(const bf16x8*)&lds_v[cur + 2*512 + lane*8];
      bf16x8 v3 = *(const bf16x8*)&lds_v[cur + 3*512 + lane*8];
      o0 = __builtin_amdgcn_mfma_f32_32x32x16_bf16(v2, pu.b, o0, 0, 0, 0);
      o1 = __builtin_amdgcn_mfma_f32_32x32x16_bf16(v3, pu.b, o1, 0, 0, 0);
    }
    __builtin_amdgcn_s_setprio(0);

    __builtin_amdgcn_sched_barrier(0);
    __builtin_amdgcn_s_barrier();
    __builtin_amdgcn_sched_barrier(0);
  }

  lrun += __shfl_xor(lrun, 32);
  float inv = 1.f / lrun;
  bf16* aop = ao_g + ((size_t)(b_*SSEQ) + q0 + ql) * DIMN + h*HD;
  #pragma unroll
  for (int g = 0; g < 4; ++g) {
    int dbase = 8*g + 4*hi;
    bf16x4 w0 = {(bf16)(o0[4*g]*inv), (bf16)(o0[4*g+1]*inv),
                 (bf16)(o0[4*g+2]*inv), (bf16)(o0[4*g+3]*inv)};
    *(bf16x4*)&aop[dbase] = w0;
    bf16x4 w1 = {(bf16)(o1[4*g]*inv), (bf16)(o1[4*g+1]*inv),
                 (bf16)(o1[4*g+2]*inv), (bf16)(o1[4*g+3]*inv)};
    *(bf16x4*)&aop[32 + dbase] = w1;
  }
}

// ---------------------------------------------------------------------------
// Workspace layout (bytes), max footprint 126,353,408:
//   wt   [0,        8388608)   8MB  weight^T staging (w_qkv/w_ao/w_gate/w_ffo)
//   rope [8388608,  8912896)   0.5MB
//   xb   [8912896, 17301504)   8MB  x bf16; reused as AO after attn
//   qkv  [17301504,42467328)  24MB  QF/KF/VF fragment layouts
//   P1   [17301504,50855936)  32MB  out-proj split-2 partials (qkv dead)
//   wt2  [50855936,59244544)   8MB  w_lin^T (during fused FFN1)
//   h1b  [84410368,92798976)   8MB  rmsnorm1 bf16 out
//   ffb  [8912896, 42467328)  32MB  swiglu out (ao/qkv/P1 dead)
//   P2   [42467328,109576192) 64MB  ff-out split-4 partials (wt2/h1b dead)
//   h1f  [109576192,126353408)16MB  rmsnorm1 f32 out (long-lived resid)
extern "C" void kernel_launch(void* const* d_in, const int* in_sizes, int n_in,
                              void* d_out, int out_size, void* d_ws, size_t ws_size,
                              hipStream_t stream) {
  const float* x      = (const float*)d_in[0];
  const float* w_qkv  = (const float*)d_in[1];
  const float* w_ao   = (const float*)d_in[2];
  const float* w_gate = (const float*)d_in[3];
  const float* b_gate = (const float*)d_in[4];
  const float* w_lin  = (const float*)d_in[5];
  const float* b_lin  = (const float*)d_in[6];
  const float* w_ffo  = (const float*)d_in[7];
  const float* scale1 = (const float*)d_in[8];
  const float* scale2 = (const float*)d_in[9];
  float* out = (float*)d_out;
  (void)ws_size; (void)in_sizes; (void)n_in; (void)out_size;

  uint8_t* ws = (uint8_t*)d_ws;
  bf16*  wt_ws   = (bf16*) (ws + 0);
  float* rope_ws = (float*)(ws + 8388608);
  bf16*  xb_ws   = (bf16*) (ws + 8912896);
  bf16*  ao_ws   = (bf16*) (ws + 8912896);    // reuse XB
  bf16*  q_ws    = (bf16*) (ws + 17301504);
  bf16*  k_ws    = (bf16*) (ws + 25690112);
  bf16*  v_ws    = (bf16*) (ws + 34078720);
  float* p1_ws   = (float*)(ws + 17301504);   // 32MB, reuse QKV region
  bf16*  wt2_ws  = (bf16*) (ws + 50855936);   // 8MB  w_lin^T
  bf16*  h1b_ws  = (bf16*) (ws + 84410368);   // 8MB
  bf16*  ffb_ws  = (bf16*) (ws + 8912896);    // 32MB, reuse XB/AO + QKV head
  float* p2_ws   = (float*)(ws + 42467328);   // 64MB, reuse wt2/h1b + gap
  float* h1f_ws  = (float*)(ws + 109576192);  // 16MB

  // 1. rope table + x cast + w_qkv^T
  rope_table_kernel<<<256, 256, 0, stream>>>(rope_ws);
  cast_f32_bf16<<<4096, 256, 0, stream>>>(x, xb_ws, MROWS*DIMN/4);
  transpose_cast_f32_bf16<<<dim3(3*DIMN/32, DIMN/32), dim3(32,8), 0, stream>>>(w_qkv, wt_ws, DIMN, 3*DIMN);
  // 2. QKV gemm + rope epilogue -> fragment-layout QF/KF/VF (Q pre-scaled)
  gemm_bt<0><<<dim3(24, 32), 256, 0, stream>>>(xb_ws, wt_ws, MROWS, 3*DIMN, DIMN,
                                               q_ws, k_ws, v_ws, rope_ws, nullptr);
  // 3. attention (double-buffered KV staging, counted vmcnt)
  attn_kernel<<<dim3(16, 32), 256, 0, stream>>>(q_ws, k_ws, v_ws, ao_ws);
  // 4. out-proj, split-K=2 -> f32 partials (resid folded into rmsnorm)
  transpose_cast_f32_bf16<<<dim3(DIMN/32, DIMN/32), dim3(32,8), 0, stream>>>(w_ao, wt_ws, DIMN, DIMN);
  gemm_bt<4><<<dim3(8, 32, 2), 256, 0, stream>>>(ao_ws, wt_ws, MROWS, DIMN, DIMN,
                                                 p1_ws, nullptr, nullptr, nullptr, nullptr);
  // 5. rmsnorm1 over (p0+p1+x) -> f32 + bf16
  rmsnorm_sum_kernel<2><<<MROWS, 256, 0, stream>>>(p1_ws, x, scale1, h1f_ws, h1b_ws);
  // 6. fused FFN1 (A-ring + reg-dbuf weights + swizzle):
  //    sigmoid(h1b@Wg+bg) * (h1b@Wl+bl) -> bf16
  transpose_cast_f32_bf16<<<dim3(FFN/32, DIMN/32), dim3(32,8), 0, stream>>>(w_gate, wt_ws, DIMN, FFN);
  transpose_cast_f32_bf16<<<dim3(FFN/32, DIMN/32), dim3(32,8), 0, stream>>>(w_lin, wt2_ws, DIMN, FFN);
  gemm256_ffn1<<<dim3(32, 16), 512, 0, stream>>>(h1b_ws, wt_ws, wt2_ws, MROWS, FFN, DIMN,
                                                 ffb_ws, b_gate, b_lin);
  // 7. ff-out gemm on engine 1 (proven round-3 config), split-K=4
  transpose_cast_f32_bf16<<<dim3(DIMN/32, FFN/32), dim3(32,8), 0, stream>>>(w_ffo, wt_ws, FFN, DIMN);
  gemm_bt<4><<<dim3(8, 32, 4), 256, 0, stream>>>(ffb_ws, wt_ws, MROWS, DIMN, FFN,
                                                 p2_ws, nullptr, nullptr, nullptr, nullptr);
  // 8. rmsnorm2 over (p0+p1+p2+p3+h1f) -> output (f32)
  rmsnorm_sum_kernel<4><<<MROWS, 256, 0, stream>>>(p2_ws, h1f_ws, scale2, out, nullptr);
}

// Round 7
// 308.701 us; speedup vs baseline: 1.1291x; 1.1291x over previous
//
#include <hip/hip_runtime.h>
#include <stdint.h>

#define DIMN 1024
#define NH 16
#define HD 64
#define FFN 4096
#define BBATCH 2
#define SSEQ 2048
#define MROWS (BBATCH*SSEQ)   // 4096

typedef __bf16 bf16;
typedef __bf16 bf16x8 __attribute__((ext_vector_type(8)));
typedef __bf16 bf16x4 __attribute__((ext_vector_type(4)));
typedef float f32x4 __attribute__((ext_vector_type(4)));
typedef float f32x16 __attribute__((ext_vector_type(16)));
typedef uint32_t u32x4 __attribute__((ext_vector_type(4)));

#define AS1 __attribute__((address_space(1)))
#define AS3 __attribute__((address_space(3)))

__device__ __forceinline__ void gload16(const bf16* g, bf16* l) {
  __builtin_amdgcn_global_load_lds((AS1 const void*)g, (AS3 void*)l, 16, 0, 0);
}

__device__ __forceinline__ uint32_t pkbf(float a, float b) {
  union { bf16 h[2]; uint32_t u; } x;
  x.h[0] = (bf16)a; x.h[1] = (bf16)b;
  return x.u;
}

// ---------------- rope table: tab[s*64 + d] = cos, tab[s*64+32+d] = sin ----
__global__ void rope_table_kernel(float* __restrict__ tab) {
  int i = blockIdx.x * blockDim.x + threadIdx.x;   // 0..65535
  int s = i >> 5, d = i & 31;
  float invf = exp2f(-(float)d * 0.4152410118609203f);
  float fr = (float)s * invf;
  tab[s*64 + d]      = cosf(fr);
  tab[s*64 + 32 + d] = sinf(fr);
}

// ---------------- f32 -> bf16 cast (vector x4) -----------------------------
__global__ void cast_f32_bf16(const float* __restrict__ in, bf16* __restrict__ out, int n4) {
  int i = blockIdx.x * blockDim.x + threadIdx.x;
  if (i < n4) {
    f32x4 v = ((const f32x4*)in)[i];
    bf16x4 o = {(bf16)v.x, (bf16)v.y, (bf16)v.z, (bf16)v.w};
    ((bf16x4*)out)[i] = o;
  }
}

// ---------------- transpose + cast: f32 [R][C] -> bf16 [C][R] --------------
__global__ __launch_bounds__(256) void transpose_cast_f32_bf16(
    const float* __restrict__ in, bf16* __restrict__ out, int R, int C) {
  __shared__ float t[32][33];
  int bx = blockIdx.x, by = blockIdx.y;
  int x = threadIdx.x, y = threadIdx.y;     // (32, 8)
  #pragma unroll
  for (int j = 0; j < 4; ++j) {
    int r = by*32 + y*4 + j;
    t[y*4+j][x] = in[(size_t)r*C + bx*32 + x];
  }
  __syncthreads();
  #pragma unroll
  for (int j = 0; j < 4; ++j) {
    int c = bx*32 + y*4 + j;
    out[(size_t)c*R + by*32 + x] = (bf16)t[x][y*4+j];
  }
}

// ---------------- pack W [K][N] f32 -> MFMA fragment layout bf16 -----------
// WF[(((cb*(K/32) + kt)*4 + n)*64 + lane)*8 + j]
//   = W[kt*32 + (lane>>4)*8 + j][cb*64 + n*16 + (lane&15)]
// so a wave's B-fragment (16x16x32 shape, frag n, K-tile kt, col-block cb)
// is one contiguous 1KB read.
__global__ __launch_bounds__(256) void pack_wfrag(
    const float* __restrict__ W, bf16* __restrict__ WF, int K, int N) {
  int g = blockIdx.x * 4 + (threadIdx.x >> 6);
  int l = threadIdx.x & 63;
  int KT = K >> 5;
  int n  = g & 3;
  int kt = (g >> 2) % KT;
  int cb = (g >> 2) / KT;
  int c  = cb*64 + n*16 + (l & 15);
  int k0 = kt*32 + (l >> 4)*8;
  bf16x8 v;
  #pragma unroll
  for (int j = 0; j < 8; ++j) v[j] = (bf16)W[(size_t)(k0 + j)*N + c];
  *(bf16x8*)&WF[((size_t)g*64 + l)*8] = v;
}

// ---------------- RMSNorm over (sum of NP partials + resid) ----------------
template<int NP>
__global__ __launch_bounds__(256) void rmsnorm_sum_kernel(
    const float* __restrict__ parts, const float* __restrict__ resid,
    const float* __restrict__ sc,
    float* __restrict__ outf, bf16* __restrict__ outb) {
  int row = blockIdx.x;
  int tid = threadIdx.x;
  size_t off = (size_t)row * DIMN;
  f32x4 v = ((const f32x4*)(resid + off))[tid];
  #pragma unroll
  for (int p = 0; p < NP; ++p) {
    f32x4 a = ((const f32x4*)(parts + (size_t)p * MROWS * DIMN + off))[tid];
    v.x += a.x; v.y += a.y; v.z += a.z; v.w += a.w;
  }
  float ss = v.x*v.x + v.y*v.y + v.z*v.z + v.w*v.w;
  #pragma unroll
  for (int m = 1; m < 64; m <<= 1) ss += __shfl_xor(ss, m);
  __shared__ float red[4];
  if ((tid & 63) == 0) red[tid >> 6] = ss;
  __syncthreads();
  float tot = red[0] + red[1] + red[2] + red[3];
  float inv = 1.f / (sqrtf(tot) * 0.03125f + 1e-8f);
  f32x4 s4 = ((const f32x4*)sc)[tid];
  f32x4 o = {v.x*s4.x*inv, v.y*s4.y*inv, v.z*s4.z*inv, v.w*s4.w*inv};
  if (outf) ((f32x4*)(outf + off))[tid] = o;
  if (outb) {
    bf16x4 ob = {(bf16)o.x, (bf16)o.y, (bf16)o.z, (bf16)o.w};
    ((bf16x4*)(outb + off))[tid] = ob;
  }
}

// ---------------- GEMM engine 1: 128x128 tile, 4 waves ---------------------
// EPI 0: QKV+rope -> fragment-layout Q/K/V (Q pre-scaled by 0.125*log2e)
// EPI 4: f32 partial: o0[z*M*N + r*N + c] = acc   (split-K)
template<int EPI>
__global__ void __launch_bounds__(256, 2) gemm_bt(
    const bf16* __restrict__ A, const bf16* __restrict__ B,
    int M, int N, int K,
    void* __restrict__ o0, void* __restrict__ o1, void* __restrict__ o2,
    const void* __restrict__ a0, const void* __restrict__ a1) {
  __shared__ __align__(16) bf16 sh_a[2*4096];
  __shared__ __align__(16) bf16 sh_b[2*4096];
  const int tid  = threadIdx.x;
  const int lane = tid & 63;
  const int wid  = tid >> 6;

  int gx  = gridDim.x;
  int bid = blockIdx.y * gx + blockIdx.x;
  int nwg = gx * gridDim.y;
  int cpx = nwg >> 3;
  int swz = (bid & 7) * cpx + (bid >> 3);
  int bxi = swz % gx, byi = swz / gx;

  const int m0 = byi * 128, n0 = bxi * 128;
  const int wm = (wid >> 1) * 64, wn = (wid & 1) * 64;

  const int kb = blockIdx.z;
  const int KC = K / (int)gridDim.z;

  f32x4 acc[4][4] = {};

  const bf16* a_base = A + (size_t)m0 * K + (size_t)kb * KC;
  const bf16* b_base = B + (size_t)n0 * K + (size_t)kb * KC;

  auto stage = [&](int kt, int buf) {
    const int lb = buf * 4096;
    #pragma unroll
    for (int i = 0; i < 2; ++i) {
      int idx = i*256 + tid;
      size_t go = (size_t)(idx >> 2)*K + (size_t)kt*32 + (idx & 3)*8;
      gload16(a_base + go, &sh_a[lb + idx*8]);
    }
    #pragma unroll
    for (int i = 0; i < 2; ++i) {
      int idx = i*256 + tid;
      size_t go = (size_t)(idx >> 2)*K + (size_t)kt*32 + (idx & 3)*8;
      gload16(b_base + go, &sh_b[lb + idx*8]);
    }
  };

  const int nsteps = KC >> 5;
  stage(0, 0);
  for (int t = 0; t < nsteps; ++t) {
    const int cb = t & 1;
    if (t + 1 < nsteps) {
      stage(t+1, cb ^ 1);
      asm volatile("s_waitcnt vmcnt(4)" ::: "memory");
    } else {
      asm volatile("s_waitcnt vmcnt(0)" ::: "memory");
    }
    __builtin_amdgcn_sched_barrier(0);
    __builtin_amdgcn_s_barrier();
    __builtin_amdgcn_sched_barrier(0);

    const int lb = cb * 4096;
    bf16x8 af[4], bfr[4];
    #pragma unroll
    for (int m = 0; m < 4; ++m)
      af[m] = *(const bf16x8*)&sh_a[lb + (wm + m*16 + (lane & 15))*32 + (lane >> 4)*8];
    #pragma unroll
    for (int n = 0; n < 4; ++n)
      bfr[n] = *(const bf16x8*)&sh_b[lb + (wn + n*16 + (lane & 15))*32 + (lane >> 4)*8];
    __builtin_amdgcn_s_setprio(1);
    #pragma unroll
    for (int m = 0; m < 4; ++m)
      #pragma unroll
      for (int n = 0; n < 4; ++n)
        acc[m][n] = __builtin_amdgcn_mfma_f32_16x16x32_bf16(af[m], bfr[n], acc[m][n], 0, 0, 0);
    __builtin_amdgcn_s_setprio(0);
    __builtin_amdgcn_sched_barrier(0);
    __builtin_amdgcn_s_barrier();
  }

  const int rq = (lane >> 4) * 4;
  const int cl = lane & 15;

  if constexpr (EPI == 0) {
    bf16* q_p = (bf16*)o0; bf16* k_p = (bf16*)o1; bf16* v_p = (bf16*)o2;
    const float* rope = (const float*)a0;
    int sec = (n0 + wn) >> 10;             // 0=q, 1=k, 2=v
    int h   = ((n0 + wn) & 1023) >> 6;
    const float qsc = (sec == 0) ? 0.18033688011112042f : 1.0f;  // 0.125*log2(e)
    #pragma unroll
    for (int m = 0; m < 4; ++m) {
      #pragma unroll
      for (int reg = 0; reg < 4; ++reg) {
        int r  = m0 + wm + m*16 + rq + reg;
        int b_ = r >> 11, s_ = r & 2047;
        int tile = s_ >> 5;
        size_t tb = ((size_t)(b_*NH + h) * 64 + tile) * 2048;  // 4KB tile base
        if (sec == 2) {
          int kvl = s_ & 31;
          int ks = kvl >> 4, hiv = (kvl >> 3) & 1, jv = kvl & 7;
          #pragma unroll
          for (int n = 0; n < 4; ++n) {
            int half = n >> 1;
            int qlv  = (n & 1) * 16 + cl;
            v_p[tb + (size_t)(ks*2 + half)*512 + (hiv*32 + qlv)*8 + jv] =
                (bf16)acc[m][n][reg];
          }
        } else {
          int qlt = s_ & 31;
          bf16* dst = (sec == 0 ? q_p : k_p);
          int lo = ((cl >> 3) * 32 + qlt) * 8 + (cl & 7);
          #pragma unroll
          for (int n = 0; n < 2; ++n) {
            int d1 = n*16 + cl;
            float c1 = rope[s_*64 + d1];
            float s1 = rope[s_*64 + 32 + d1];
            float x1 = acc[m][n][reg], x2 = acc[m][n+2][reg];
            dst[tb + (size_t)n*512 + lo]       = (bf16)((x1*c1 - x2*s1) * qsc);
            dst[tb + (size_t)(n+2)*512 + lo]   = (bf16)((x1*s1 + x2*c1) * qsc);
          }
        }
      }
    }
  } else if constexpr (EPI == 4) {
    float* op = (float*)o0 + (size_t)kb * M * N;
    #pragma unroll
    for (int m = 0; m < 4; ++m)
      #pragma unroll
      for (int n = 0; n < 4; ++n)
        #pragma unroll
        for (int reg = 0; reg < 4; ++reg) {
          int r = m0 + wm + m*16 + rq + reg;
          int c = n0 + wn + n*16 + cl;
          op[(size_t)r*N + c] = acc[m][n][reg];
        }
  }
}

// ---------------- fused FFN1, reg-weights (128x128 chassis) ----------------
// A (activations) staged via gload_lds into 16KB dbuf LDS (the r3-proven
// pipeline); gate/lin weights read DIRECTLY into registers from the
// fragment-packed WF layout (1KB contiguous per fragment -> fully
// coalesced, L2-resident), 1-tile register double-buffer. Per iter:
// issue ldW(t+1)[8 ops] then stageA(t+1)[2 ops]; vmcnt(10) ensures tile
// t fully landed while t+1's 10 stay in flight. Register copy bnxt->bcur
// sits AFTER the MFMA phase (compiler inserts vmcnt(2) there; W loads had
// the whole compute phase to land).
__global__ void __launch_bounds__(256, 2) gemm_ffn1_rw(
    const bf16* __restrict__ A, const bf16* __restrict__ WgF,
    const bf16* __restrict__ WlF, int M, int N, int K,
    bf16* __restrict__ o0, const float* __restrict__ bgv,
    const float* __restrict__ blv) {
  __shared__ __align__(16) bf16 sh_a[2*4096];
  const int tid  = threadIdx.x;
  const int lane = tid & 63;
  const int wid  = tid >> 6;

  int gx  = gridDim.x;
  int bid = blockIdx.y * gx + blockIdx.x;
  int nwg = gx * gridDim.y;
  int cpx = nwg >> 3;
  int swz = (bid & 7) * cpx + (bid >> 3);
  int bxi = swz % gx, byi = swz / gx;

  const int m0 = byi * 128, n0 = bxi * 128;
  const int wm = (wid >> 1) * 64, wn = (wid & 1) * 64;

  const int KT = K >> 5;                 // 32 K-tiles
  const int wcb = (n0 + wn) >> 6;        // wave's 64-col block index
  const bf16* wg = WgF + (size_t)wcb * KT * 2048;
  const bf16* wl = WlF + (size_t)wcb * KT * 2048;
  const bf16* a_base = A + (size_t)m0 * K;

  auto stageA = [&](int kt, int buf) {
    #pragma unroll
    for (int i = 0; i < 2; ++i) {
      int idx = i*256 + tid;
      size_t go = (size_t)(idx >> 2)*K + (size_t)kt*32 + (idx & 3)*8;
      gload16(a_base + go, &sh_a[buf*4096 + idx*8]);
    }
  };
  auto ldW = [&](int kt, bf16x8* bb, bf16x8* cc) {
    #pragma unroll
    for (int n = 0; n < 4; ++n) {
      bb[n] = *(const bf16x8*)&wg[(size_t)kt*2048 + n*512 + lane*8];
      cc[n] = *(const bf16x8*)&wl[(size_t)kt*2048 + n*512 + lane*8];
    }
  };

  f32x4 acc[4][4] = {}, acc2[4][4] = {};
  bf16x8 bcur[4], ccur[4], bnxt[4], cnxt[4];

  ldW(0, bcur, ccur);
  stageA(0, 0);
  for (int t = 0; t < KT; ++t) {
    const int cb = t & 1;
    if (t + 1 < KT) {
      ldW(t+1, bnxt, cnxt);     // 8 VMEM (older of the new batch)
      stageA(t+1, cb ^ 1);      // 2 VMEM (newest)
      asm volatile("s_waitcnt vmcnt(10)" ::: "memory");  // tile t landed
    } else {
      asm volatile("s_waitcnt vmcnt(0)" ::: "memory");
    }
    __builtin_amdgcn_sched_barrier(0);
    __builtin_amdgcn_s_barrier();
    __builtin_amdgcn_sched_barrier(0);

    const int lb = cb * 4096;
    bf16x8 af[4];
    #pragma unroll
    for (int m = 0; m < 4; ++m)
      af[m] = *(const bf16x8*)&sh_a[lb + (wm + m*16 + (lane & 15))*32 + (lane >> 4)*8];
    __builtin_amdgcn_s_setprio(1);
    #pragma unroll
    for (int m = 0; m < 4; ++m)
      #pragma unroll
      for (int n = 0; n < 4; ++n) {
        acc [m][n] = __builtin_amdgcn_mfma_f32_16x16x32_bf16(af[m], bcur[n], acc [m][n], 0, 0, 0);
        acc2[m][n] = __builtin_amdgcn_mfma_f32_16x16x32_bf16(af[m], ccur[n], acc2[m][n], 0, 0, 0);
      }
    __builtin_amdgcn_s_setprio(0);
    __builtin_amdgcn_sched_barrier(0);
    __builtin_amdgcn_s_barrier();       // all waves done reading buf cb
    if (t + 1 < KT) {
      #pragma unroll
      for (int n = 0; n < 4; ++n) { bcur[n] = bnxt[n]; ccur[n] = cnxt[n]; }
    }
  }

  const int rq = (lane >> 4) * 4;
  const int cl = lane & 15;
  #pragma unroll
  for (int m = 0; m < 4; ++m)
    #pragma unroll
    for (int n = 0; n < 4; ++n)
      #pragma unroll
      for (int reg = 0; reg < 4; ++reg) {
        int r = m0 + wm + m*16 + rq + reg;
        int c = n0 + wn + n*16 + cl;
        float gv = acc [m][n][reg] + bgv[c];
        float lv = acc2[m][n][reg] + blv[c];
        float sg = 1.f / (1.f + __expf(-gv));
        o0[(size_t)r*N + c] = (bf16)(sg * lv);
      }
}

// ---------------- fused attention (no-max softmax, fragment-layout inputs) -
__global__ void __launch_bounds__(256) attn_kernel(
    const bf16* __restrict__ qf_g, const bf16* __restrict__ kf_g,
    const bf16* __restrict__ vf_g, bf16* __restrict__ ao_g) {
  __shared__ __align__(16) bf16 lds_k[2*2048];
  __shared__ __align__(16) bf16 lds_v[2*2048];
  const int tid  = threadIdx.x;
  const int lane = tid & 63;
  const int qw   = tid >> 6;      // wave's 32-row q group (0..3)
  const int hi   = lane >> 5;
  const int ql   = lane & 31;
  const int bh   = blockIdx.y;
  const int b_   = bh >> 4, h = bh & 15;
  const int q0   = blockIdx.x * 128 + qw * 32;
  const int qt   = blockIdx.x * 4 + qw;

  const bf16* qtile = qf_g + ((size_t)bh*64 + qt) * 2048;
  const bf16* kbase = kf_g + (size_t)bh * 64 * 2048;
  const bf16* vbase = vf_g + (size_t)bh * 64 * 2048;

  bf16x8 qf[4];
  #pragma unroll
  for (int ds = 0; ds < 4; ++ds)
    qf[ds] = *(const bf16x8*)&qtile[ds*512 + lane*8];

  f32x16 o0 = {}, o1 = {};
  float lrun = 0.f;

  gload16(kbase + tid*8, &lds_k[tid*8]);
  gload16(vbase + tid*8, &lds_v[tid*8]);

  for (int t = 0; t < 64; ++t) {
    const int cur = (t & 1) * 2048;
    if (t < 63) {
      const int nxt = 2048 - cur;
      gload16(kbase + (size_t)(t+1)*2048 + tid*8, &lds_k[nxt + tid*8]);
      gload16(vbase + (size_t)(t+1)*2048 + tid*8, &lds_v[nxt + tid*8]);
      asm volatile("s_waitcnt vmcnt(2)" ::: "memory");
    } else {
      asm volatile("s_waitcnt vmcnt(0)" ::: "memory");
    }
    __builtin_amdgcn_sched_barrier(0);
    __builtin_amdgcn_s_barrier();
    __builtin_amdgcn_sched_barrier(0);

    f32x16 st = {};
    __builtin_amdgcn_s_setprio(1);
    #pragma unroll
    for (int ds = 0; ds < 4; ++ds) {
      bf16x8 kf = *(const bf16x8*)&lds_k[cur + ds*512 + lane*8];
      st = __builtin_amdgcn_mfma_f32_32x32x16_bf16(kf, qf[ds], st, 0, 0, 0);
    }
    __builtin_amdgcn_s_setprio(0);
    float p[16];
    float psum = 0.f;
    #pragma unroll
    for (int r = 0; r < 16; ++r) { p[r] = __builtin_amdgcn_exp2f(st[r]); psum += p[r]; }
    lrun += psum;

    uint32_t w0 = pkbf(p[0],p[1]),   w1 = pkbf(p[2],p[3]);
    uint32_t w2 = pkbf(p[4],p[5]),   w3 = pkbf(p[6],p[7]);
    uint32_t w4 = pkbf(p[8],p[9]),   w5 = pkbf(p[10],p[11]);
    uint32_t w6 = pkbf(p[12],p[13]), w7 = pkbf(p[14],p[15]);
    asm("v_permlane32_swap_b32 %0, %1" : "+v"(w0), "+v"(w2));
    asm("v_permlane32_swap_b32 %0, %1" : "+v"(w1), "+v"(w3));
    asm("v_permlane32_swap_b32 %0, %1" : "+v"(w4), "+v"(w6));
    asm("v_permlane32_swap_b32 %0, %1" : "+v"(w5), "+v"(w7));

    __builtin_amdgcn_s_setprio(1);
    {
      union { u32x4 u; bf16x8 b; } pu;
      u32x4 pwa = {w0, w1, w2, w3};
      pu.u = pwa;
      bf16x8 v0 = *(const bf16x8*)&lds_v[cur + 0*512 + lane*8];
      bf16x8 v1 = *(const bf16x8*)&lds_v[cur + 1*512 + lane*8];
      o0 = __builtin_amdgcn_mfma_f32_32x32x16_bf16(v0, pu.b, o0, 0, 0, 0);
      o1 = __builtin_amdgcn_mfma_f32_32x32x16_bf16(v1, pu.b, o1, 0, 0, 0);
      u32x4 pwb = {w4, w5, w6, w7};
      pu.u = pwb;
      bf16x8 v2 = *(const bf16x8*)&lds_v[cur + 2*512 + lane*8];
      bf16x8 v3 = *(const bf16x8*)&lds_v[cur + 3*512 + lane*8];
      o0 = __builtin_amdgcn_mfma_f32_32x32x16_bf16(v2, pu.b, o0, 0, 0, 0);
      o1 = __builtin_amdgcn_mfma_f32_32x32x16_bf16(v3, pu.b, o1, 0, 0, 0);
    }
    __builtin_amdgcn_s_setprio(0);

    __builtin_amdgcn_sched_barrier(0);
    __builtin_amdgcn_s_barrier();
    __builtin_amdgcn_sched_barrier(0);
  }

  lrun += __shfl_xor(lrun, 32);
  float inv = 1.f / lrun;
  bf16* aop = ao_g + ((size_t)(b_*SSEQ) + q0 + ql) * DIMN + h*HD;
  #pragma unroll
  for (int g = 0; g < 4; ++g) {
    int dbase = 8*g + 4*hi;
    bf16x4 w0 = {(bf16)(o0[4*g]*inv), (bf16)(o0[4*g+1]*inv),
                 (bf16)(o0[4*g+2]*inv), (bf16)(o0[4*g+3]*inv)};
    *(bf16x4*)&aop[dbase] = w0;
    bf16x4 w1 = {(bf16)(o1[4*g]*inv), (bf16)(o1[4*g+1]*inv),
                 (bf16)(o1[4*g+2]*inv), (bf16)(o1[4*g+3]*inv)};
    *(bf16x4*)&aop[32 + dbase] = w1;
  }
}

// ---------------------------------------------------------------------------
// Workspace layout (bytes), max footprint 126,353,408:
//   wt   [0,        8388608)   8MB  weight staging (w_qkv^T/w_ao^T/WgF/w_ffo^T)
//   rope [8388608,  8912896)   0.5MB
//   xb   [8912896, 17301504)   8MB  x bf16; reused as AO after attn
//   qkv  [17301504,42467328)  24MB  QF/KF/VF fragment layouts
//   P1   [17301504,50855936)  32MB  out-proj split-2 partials (qkv dead)
//   wt2  [50855936,59244544)   8MB  WlF (during fused FFN1)
//   h1b  [84410368,92798976)   8MB  rmsnorm1 bf16 out
//   ffb  [8912896, 42467328)  32MB  swiglu out (ao/qkv/P1 dead)
//   P2   [42467328,109576192) 64MB  ff-out split-4 partials (wt2/h1b dead)
//   h1f  [109576192,126353408)16MB  rmsnorm1 f32 out (long-lived resid)
extern "C" void kernel_launch(void* const* d_in, const int* in_sizes, int n_in,
                              void* d_out, int out_size, void* d_ws, size_t ws_size,
                              hipStream_t stream) {
  const float* x      = (const float*)d_in[0];
  const float* w_qkv  = (const float*)d_in[1];
  const float* w_ao   = (const float*)d_in[2];
  const float* w_gate = (const float*)d_in[3];
  const float* b_gate = (const float*)d_in[4];
  const float* w_lin  = (const float*)d_in[5];
  const float* b_lin  = (const float*)d_in[6];
  const float* w_ffo  = (const float*)d_in[7];
  const float* scale1 = (const float*)d_in[8];
  const float* scale2 = (const float*)d_in[9];
  float* out = (float*)d_out;
  (void)ws_size; (void)in_sizes; (void)n_in; (void)out_size;

  uint8_t* ws = (uint8_t*)d_ws;
  bf16*  wt_ws   = (bf16*) (ws + 0);
  float* rope_ws = (float*)(ws + 8388608);
  bf16*  xb_ws   = (bf16*) (ws + 8912896);
  bf16*  ao_ws   = (bf16*) (ws + 8912896);    // reuse XB
  bf16*  q_ws    = (bf16*) (ws + 17301504);
  bf16*  k_ws    = (bf16*) (ws + 25690112);
  bf16*  v_ws    = (bf16*) (ws + 34078720);
  float* p1_ws   = (float*)(ws + 17301504);   // 32MB, reuse QKV region
  bf16*  wt2_ws  = (bf16*) (ws + 50855936);   // 8MB  WlF
  bf16*  h1b_ws  = (bf16*) (ws + 84410368);   // 8MB
  bf16*  ffb_ws  = (bf16*) (ws + 8912896);    // 32MB, reuse XB/AO + QKV head
  float* p2_ws   = (float*)(ws + 42467328);   // 64MB, reuse wt2/h1b + gap
  float* h1f_ws  = (float*)(ws + 109576192);  // 16MB

  // 1. rope table + x cast + w_qkv^T
  rope_table_kernel<<<256, 256, 0, stream>>>(rope_ws);
  cast_f32_bf16<<<4096, 256, 0, stream>>>(x, xb_ws, MROWS*DIMN/4);
  transpose_cast_f32_bf16<<<dim3(3*DIMN/32, DIMN/32), dim3(32,8), 0, stream>>>(w_qkv, wt_ws, DIMN, 3*DIMN);
  // 2. QKV gemm + rope epilogue -> fragment-layout QF/KF/VF (Q pre-scaled)
  gemm_bt<0><<<dim3(24, 32), 256, 0, stream>>>(xb_ws, wt_ws, MROWS, 3*DIMN, DIMN,
                                               q_ws, k_ws, v_ws, rope_ws, nullptr);
  // 3. attention (double-buffered KV staging, counted vmcnt)
  attn_kernel<<<dim3(16, 32), 256, 0, stream>>>(q_ws, k_ws, v_ws, ao_ws);
  // 4. out-proj, split-K=2 -> f32 partials (resid folded into rmsnorm)
  transpose_cast_f32_bf16<<<dim3(DIMN/32, DIMN/32), dim3(32,8), 0, stream>>>(w_ao, wt_ws, DIMN, DIMN);
  gemm_bt<4><<<dim3(8, 32, 2), 256, 0, stream>>>(ao_ws, wt_ws, MROWS, DIMN, DIMN,
                                                 p1_ws, nullptr, nullptr, nullptr, nullptr);
  // 5. rmsnorm1 over (p0+p1+x) -> f32 + bf16
  rmsnorm_sum_kernel<2><<<MROWS, 256, 0, stream>>>(p1_ws, x, scale1, h1f_ws, h1b_ws);
  // 6. fused FFN1, reg-weights: pack w_gate/w_lin into fragment layout,
  //    then sigmoid(h1b@Wg+bg) * (h1b@Wl+bl) -> bf16
  pack_wfrag<<<2048, 256, 0, stream>>>(w_gate, wt_ws, DIMN, FFN);
  pack_wfrag<<<2048, 256, 0, stream>>>(w_lin, wt2_ws, DIMN, FFN);
  gemm_ffn1_rw<<<dim3(32, 32), 256, 0, stream>>>(h1b_ws, wt_ws, wt2_ws, MROWS, FFN, DIMN,
                                                 ffb_ws, b_gate, b_lin);
  // 7. ff-out gemm on engine 1 (proven round-3 config), split-K=4
  transpose_cast_f32_bf16<<<dim3(DIMN/32, FFN/32), dim3(32,8), 0, stream>>>(w_ffo, wt_ws, FFN, DIMN);
  gemm_bt<4><<<dim3(8, 32, 4), 256, 0, stream>>>(ffb_ws, wt_ws, MROWS, DIMN, FFN,
                                                 p2_ws, nullptr, nullptr, nullptr, nullptr);
  // 8. rmsnorm2 over (p0+p1+p2+p3+h1f) -> output (f32)
  rmsnorm_sum_kernel<4><<<MROWS, 256, 0, stream>>>(p2_ws, h1f_ws, scale2, out, nullptr);
}

// Round 8
// 304.302 us; speedup vs baseline: 1.1454x; 1.0145x over previous
//
#include <hip/hip_runtime.h>
#include <stdint.h>

#define DIMN 1024
#define NH 16
#define HD 64
#define FFN 4096
#define BBATCH 2
#define SSEQ 2048
#define MROWS (BBATCH*SSEQ)   // 4096

typedef __bf16 bf16;
typedef __bf16 bf16x8 __attribute__((ext_vector_type(8)));
typedef __bf16 bf16x4 __attribute__((ext_vector_type(4)));
typedef float f32x4 __attribute__((ext_vector_type(4)));
typedef float f32x16 __attribute__((ext_vector_type(16)));
typedef uint32_t u32x4 __attribute__((ext_vector_type(4)));

#define AS1 __attribute__((address_space(1)))
#define AS3 __attribute__((address_space(3)))

__device__ __forceinline__ void gload16(const bf16* g, bf16* l) {
  __builtin_amdgcn_global_load_lds((AS1 const void*)g, (AS3 void*)l, 16, 0, 0);
}

__device__ __forceinline__ uint32_t pkbf(float a, float b) {
  union { bf16 h[2]; uint32_t u; } x;
  x.h[0] = (bf16)a; x.h[1] = (bf16)b;
  return x.u;
}

// ---------------- rope table: tab[s*64 + d] = cos, tab[s*64+32+d] = sin ----
__global__ void rope_table_kernel(float* __restrict__ tab) {
  int i = blockIdx.x * blockDim.x + threadIdx.x;   // 0..65535
  int s = i >> 5, d = i & 31;
  float invf = exp2f(-(float)d * 0.4152410118609203f);
  float fr = (float)s * invf;
  tab[s*64 + d]      = cosf(fr);
  tab[s*64 + 32 + d] = sinf(fr);
}

// ---------------- f32 -> bf16 cast (vector x4) -----------------------------
__global__ void cast_f32_bf16(const float* __restrict__ in, bf16* __restrict__ out, int n4) {
  int i = blockIdx.x * blockDim.x + threadIdx.x;
  if (i < n4) {
    f32x4 v = ((const f32x4*)in)[i];
    bf16x4 o = {(bf16)v.x, (bf16)v.y, (bf16)v.z, (bf16)v.w};
    ((bf16x4*)out)[i] = o;
  }
}

// ---------------- pack W [K][N] f32 -> MFMA fragment layout bf16 -----------
// WF[(((cb*(K/32) + kt)*4 + n)*64 + lane)*8 + j]
//   = W[kt*32 + (lane>>4)*8 + j][cb*64 + n*16 + (lane&15)]
// so a wave's B-fragment (16x16x32 shape, frag n, K-tile kt, col-block cb)
// is one contiguous 1KB read.
__global__ __launch_bounds__(256) void pack_wfrag(
    const float* __restrict__ W, bf16* __restrict__ WF, int K, int N) {
  int g = blockIdx.x * 4 + (threadIdx.x >> 6);
  int l = threadIdx.x & 63;
  int KT = K >> 5;
  int n  = g & 3;
  int kt = (g >> 2) % KT;
  int cb = (g >> 2) / KT;
  int c  = cb*64 + n*16 + (l & 15);
  int k0 = kt*32 + (l >> 4)*8;
  bf16x8 v;
  #pragma unroll
  for (int j = 0; j < 8; ++j) v[j] = (bf16)W[(size_t)(k0 + j)*N + c];
  *(bf16x8*)&WF[((size_t)g*64 + l)*8] = v;
}

// ---------------- RMSNorm over (sum of NP partials + resid) ----------------
template<int NP>
__global__ __launch_bounds__(256) void rmsnorm_sum_kernel(
    const float* __restrict__ parts, const float* __restrict__ resid,
    const float* __restrict__ sc,
    float* __restrict__ outf, bf16* __restrict__ outb) {
  int row = blockIdx.x;
  int tid = threadIdx.x;
  size_t off = (size_t)row * DIMN;
  f32x4 v = ((const f32x4*)(resid + off))[tid];
  #pragma unroll
  for (int p = 0; p < NP; ++p) {
    f32x4 a = ((const f32x4*)(parts + (size_t)p * MROWS * DIMN + off))[tid];
    v.x += a.x; v.y += a.y; v.z += a.z; v.w += a.w;
  }
  float ss = v.x*v.x + v.y*v.y + v.z*v.z + v.w*v.w;
  #pragma unroll
  for (int m = 1; m < 64; m <<= 1) ss += __shfl_xor(ss, m);
  __shared__ float red[4];
  if ((tid & 63) == 0) red[tid >> 6] = ss;
  __syncthreads();
  float tot = red[0] + red[1] + red[2] + red[3];
  float inv = 1.f / (sqrtf(tot) * 0.03125f + 1e-8f);
  f32x4 s4 = ((const f32x4*)sc)[tid];
  f32x4 o = {v.x*s4.x*inv, v.y*s4.y*inv, v.z*s4.z*inv, v.w*s4.w*inv};
  if (outf) ((f32x4*)(outf + off))[tid] = o;
  if (outb) {
    bf16x4 ob = {(bf16)o.x, (bf16)o.y, (bf16)o.z, (bf16)o.w};
    ((bf16x4*)(outb + off))[tid] = ob;
  }
}

// ---------------- rw GEMM engine: 128x128 tile, 4 waves, reg-weights -------
// A staged via gload_lds into 16KB dbuf LDS; weight fragments read DIRECTLY
// into registers from the fragment-packed WF layout (1KB contiguous per
// fragment), 1-tile register double-buffer. Per iter: ldW(t+1)[4 ops] then
// stageA(t+1)[2 ops]; vmcnt(6) = tile t fully landed, t+1's 6 in flight.
// Split-K via gridDim.z (W tile index is absolute: kb*nt + t).
// EPI 0: QKV+rope -> fragment-layout Q/K/V (Q pre-scaled by 0.125*log2e)
// EPI 4: f32 partial: o0[z*M*N + r*N + c] = acc
template<int EPI>
__global__ void __launch_bounds__(256, 3) gemm_rw(
    const bf16* __restrict__ A, const bf16* __restrict__ WF,
    int M, int N, int K,
    void* __restrict__ o0, void* __restrict__ o1, void* __restrict__ o2,
    const void* __restrict__ a0) {
  __shared__ __align__(16) bf16 sh_a[2*4096];
  const int tid  = threadIdx.x;
  const int lane = tid & 63;
  const int wid  = tid >> 6;

  int gx  = gridDim.x;
  int bid = blockIdx.y * gx + blockIdx.x;
  int nwg = gx * gridDim.y;
  int cpx = nwg >> 3;
  int swz = (bid & 7) * cpx + (bid >> 3);
  int bxi = swz % gx, byi = swz / gx;

  const int m0 = byi * 128, n0 = bxi * 128;
  const int wm = (wid >> 1) * 64, wn = (wid & 1) * 64;

  const int kb = blockIdx.z;
  const int KC = K / (int)gridDim.z;
  const int KT = K >> 5;           // total K-tiles in WF layout
  const int nt = KC >> 5;          // K-tiles this block processes

  const int wcb = (n0 + wn) >> 6;  // wave's 64-col block in WF
  const bf16* wf = WF + (size_t)wcb * KT * 2048;
  const bf16* a_base = A + (size_t)m0 * K + (size_t)kb * KC;

  auto stageA = [&](int kt, int buf) {
    #pragma unroll
    for (int i = 0; i < 2; ++i) {
      int idx = i*256 + tid;
      size_t go = (size_t)(idx >> 2)*K + (size_t)kt*32 + (idx & 3)*8;
      gload16(a_base + go, &sh_a[buf*4096 + idx*8]);
    }
  };
  auto ldW = [&](int kta, bf16x8* bb) {
    #pragma unroll
    for (int n = 0; n < 4; ++n)
      bb[n] = *(const bf16x8*)&wf[(size_t)kta*2048 + n*512 + lane*8];
  };

  f32x4 acc[4][4] = {};
  bf16x8 bcur[4], bnxt[4];

  ldW(kb*nt, bcur);
  stageA(0, 0);
  for (int t = 0; t < nt; ++t) {
    const int cb = t & 1;
    if (t + 1 < nt) {
      ldW(kb*nt + t + 1, bnxt);   // 4 VMEM (older of the new batch)
      stageA(t+1, cb ^ 1);        // 2 VMEM (newest)
      asm volatile("s_waitcnt vmcnt(6)" ::: "memory");  // tile t landed
    } else {
      asm volatile("s_waitcnt vmcnt(0)" ::: "memory");
    }
    __builtin_amdgcn_sched_barrier(0);
    __builtin_amdgcn_s_barrier();
    __builtin_amdgcn_sched_barrier(0);

    const int lb = cb * 4096;
    bf16x8 af[4];
    #pragma unroll
    for (int m = 0; m < 4; ++m)
      af[m] = *(const bf16x8*)&sh_a[lb + (wm + m*16 + (lane & 15))*32 + (lane >> 4)*8];
    __builtin_amdgcn_s_setprio(1);
    #pragma unroll
    for (int m = 0; m < 4; ++m)
      #pragma unroll
      for (int n = 0; n < 4; ++n)
        acc[m][n] = __builtin_amdgcn_mfma_f32_16x16x32_bf16(af[m], bcur[n], acc[m][n], 0, 0, 0);
    __builtin_amdgcn_s_setprio(0);
    __builtin_amdgcn_sched_barrier(0);
    __builtin_amdgcn_s_barrier();       // all waves done reading buf cb
    if (t + 1 < nt) {
      #pragma unroll
      for (int n = 0; n < 4; ++n) bcur[n] = bnxt[n];
    }
  }

  const int rq = (lane >> 4) * 4;
  const int cl = lane & 15;

  if constexpr (EPI == 0) {
    bf16* q_p = (bf16*)o0; bf16* k_p = (bf16*)o1; bf16* v_p = (bf16*)o2;
    const float* rope = (const float*)a0;
    int sec = (n0 + wn) >> 10;             // 0=q, 1=k, 2=v
    int h   = ((n0 + wn) & 1023) >> 6;
    const float qsc = (sec == 0) ? 0.18033688011112042f : 1.0f;  // 0.125*log2(e)
    #pragma unroll
    for (int m = 0; m < 4; ++m) {
      #pragma unroll
      for (int reg = 0; reg < 4; ++reg) {
        int r  = m0 + wm + m*16 + rq + reg;
        int b_ = r >> 11, s_ = r & 2047;
        int tile = s_ >> 5;
        size_t tb = ((size_t)(b_*NH + h) * 64 + tile) * 2048;  // 4KB tile base
        if (sec == 2) {
          int kvl = s_ & 31;
          int ks = kvl >> 4, hiv = (kvl >> 3) & 1, jv = kvl & 7;
          #pragma unroll
          for (int n = 0; n < 4; ++n) {
            int half = n >> 1;
            int qlv  = (n & 1) * 16 + cl;
            v_p[tb + (size_t)(ks*2 + half)*512 + (hiv*32 + qlv)*8 + jv] =
                (bf16)acc[m][n][reg];
          }
        } else {
          int qlt = s_ & 31;
          bf16* dst = (sec == 0 ? q_p : k_p);
          int lo = ((cl >> 3) * 32 + qlt) * 8 + (cl & 7);
          #pragma unroll
          for (int n = 0; n < 2; ++n) {
            int d1 = n*16 + cl;
            float c1 = rope[s_*64 + d1];
            float s1 = rope[s_*64 + 32 + d1];
            float x1 = acc[m][n][reg], x2 = acc[m][n+2][reg];
            dst[tb + (size_t)n*512 + lo]       = (bf16)((x1*c1 - x2*s1) * qsc);
            dst[tb + (size_t)(n+2)*512 + lo]   = (bf16)((x1*s1 + x2*c1) * qsc);
          }
        }
      }
    }
  } else if constexpr (EPI == 4) {
    float* op = (float*)o0 + (size_t)kb * M * N;
    #pragma unroll
    for (int m = 0; m < 4; ++m)
      #pragma unroll
      for (int n = 0; n < 4; ++n)
        #pragma unroll
        for (int reg = 0; reg < 4; ++reg) {
          int r = m0 + wm + m*16 + rq + reg;
          int c = n0 + wn + n*16 + cl;
          op[(size_t)r*N + c] = acc[m][n][reg];
        }
  }
}

// ---------------- fused FFN1, reg-weights (r7 proven, unchanged) -----------
__global__ void __launch_bounds__(256, 2) gemm_ffn1_rw(
    const bf16* __restrict__ A, const bf16* __restrict__ WgF,
    const bf16* __restrict__ WlF, int M, int N, int K,
    bf16* __restrict__ o0, const float* __restrict__ bgv,
    const float* __restrict__ blv) {
  __shared__ __align__(16) bf16 sh_a[2*4096];
  const int tid  = threadIdx.x;
  const int lane = tid & 63;
  const int wid  = tid >> 6;

  int gx  = gridDim.x;
  int bid = blockIdx.y * gx + blockIdx.x;
  int nwg = gx * gridDim.y;
  int cpx = nwg >> 3;
  int swz = (bid & 7) * cpx + (bid >> 3);
  int bxi = swz % gx, byi = swz / gx;

  const int m0 = byi * 128, n0 = bxi * 128;
  const int wm = (wid >> 1) * 64, wn = (wid & 1) * 64;

  const int KT = K >> 5;                 // 32 K-tiles
  const int wcb = (n0 + wn) >> 6;        // wave's 64-col block index
  const bf16* wg = WgF + (size_t)wcb * KT * 2048;
  const bf16* wl = WlF + (size_t)wcb * KT * 2048;
  const bf16* a_base = A + (size_t)m0 * K;

  auto stageA = [&](int kt, int buf) {
    #pragma unroll
    for (int i = 0; i < 2; ++i) {
      int idx = i*256 + tid;
      size_t go = (size_t)(idx >> 2)*K + (size_t)kt*32 + (idx & 3)*8;
      gload16(a_base + go, &sh_a[buf*4096 + idx*8]);
    }
  };
  auto ldW = [&](int kt, bf16x8* bb, bf16x8* cc) {
    #pragma unroll
    for (int n = 0; n < 4; ++n) {
      bb[n] = *(const bf16x8*)&wg[(size_t)kt*2048 + n*512 + lane*8];
      cc[n] = *(const bf16x8*)&wl[(size_t)kt*2048 + n*512 + lane*8];
    }
  };

  f32x4 acc[4][4] = {}, acc2[4][4] = {};
  bf16x8 bcur[4], ccur[4], bnxt[4], cnxt[4];

  ldW(0, bcur, ccur);
  stageA(0, 0);
  for (int t = 0; t < KT; ++t) {
    const int cb = t & 1;
    if (t + 1 < KT) {
      ldW(t+1, bnxt, cnxt);     // 8 VMEM (older of the new batch)
      stageA(t+1, cb ^ 1);      // 2 VMEM (newest)
      asm volatile("s_waitcnt vmcnt(10)" ::: "memory");  // tile t landed
    } else {
      asm volatile("s_waitcnt vmcnt(0)" ::: "memory");
    }
    __builtin_amdgcn_sched_barrier(0);
    __builtin_amdgcn_s_barrier();
    __builtin_amdgcn_sched_barrier(0);

    const int lb = cb * 4096;
    bf16x8 af[4];
    #pragma unroll
    for (int m = 0; m < 4; ++m)
      af[m] = *(const bf16x8*)&sh_a[lb + (wm + m*16 + (lane & 15))*32 + (lane >> 4)*8];
    __builtin_amdgcn_s_setprio(1);
    #pragma unroll
    for (int m = 0; m < 4; ++m)
      #pragma unroll
      for (int n = 0; n < 4; ++n) {
        acc [m][n] = __builtin_amdgcn_mfma_f32_16x16x32_bf16(af[m], bcur[n], acc [m][n], 0, 0, 0);
        acc2[m][n] = __builtin_amdgcn_mfma_f32_16x16x32_bf16(af[m], ccur[n], acc2[m][n], 0, 0, 0);
      }
    __builtin_amdgcn_s_setprio(0);
    __builtin_amdgcn_sched_barrier(0);
    __builtin_amdgcn_s_barrier();       // all waves done reading buf cb
    if (t + 1 < KT) {
      #pragma unroll
      for (int n = 0; n < 4; ++n) { bcur[n] = bnxt[n]; ccur[n] = cnxt[n]; }
    }
  }

  const int rq = (lane >> 4) * 4;
  const int cl = lane & 15;
  #pragma unroll
  for (int m = 0; m < 4; ++m)
    #pragma unroll
    for (int n = 0; n < 4; ++n)
      #pragma unroll
      for (int reg = 0; reg < 4; ++reg) {
        int r = m0 + wm + m*16 + rq + reg;
        int c = n0 + wn + n*16 + cl;
        float gv = acc [m][n][reg] + bgv[c];
        float lv = acc2[m][n][reg] + blv[c];
        float sg = 1.f / (1.f + __expf(-gv));
        o0[(size_t)r*N + c] = (bf16)(sg * lv);
      }
}

// ---------------- fused attention (no-max softmax, fragment-layout inputs) -
__global__ void __launch_bounds__(256) attn_kernel(
    const bf16* __restrict__ qf_g, const bf16* __restrict__ kf_g,
    const bf16* __restrict__ vf_g, bf16* __restrict__ ao_g) {
  __shared__ __align__(16) bf16 lds_k[2*2048];
  __shared__ __align__(16) bf16 lds_v[2*2048];
  const int tid  = threadIdx.x;
  const int lane = tid & 63;
  const int qw   = tid >> 6;      // wave's 32-row q group (0..3)
  const int hi   = lane >> 5;
  const int ql   = lane & 31;
  const int bh   = blockIdx.y;
  const int b_   = bh >> 4, h = bh & 15;
  const int q0   = blockIdx.x * 128 + qw * 32;
  const int qt   = blockIdx.x * 4 + qw;

  const bf16* qtile = qf_g + ((size_t)bh*64 + qt) * 2048;
  const bf16* kbase = kf_g + (size_t)bh * 64 * 2048;
  const bf16* vbase = vf_g + (size_t)bh * 64 * 2048;

  bf16x8 qf[4];
  #pragma unroll
  for (int ds = 0; ds < 4; ++ds)
    qf[ds] = *(const bf16x8*)&qtile[ds*512 + lane*8];

  f32x16 o0 = {}, o1 = {};
  float lrun = 0.f;

  gload16(kbase + tid*8, &lds_k[tid*8]);
  gload16(vbase + tid*8, &lds_v[tid*8]);

  for (int t = 0; t < 64; ++t) {
    const int cur = (t & 1) * 2048;
    if (t < 63) {
      const int nxt = 2048 - cur;
      gload16(kbase + (size_t)(t+1)*2048 + tid*8, &lds_k[nxt + tid*8]);
      gload16(vbase + (size_t)(t+1)*2048 + tid*8, &lds_v[nxt + tid*8]);
      asm volatile("s_waitcnt vmcnt(2)" ::: "memory");
    } else {
      asm volatile("s_waitcnt vmcnt(0)" ::: "memory");
    }
    __builtin_amdgcn_sched_barrier(0);
    __builtin_amdgcn_s_barrier();
    __builtin_amdgcn_sched_barrier(0);

    f32x16 st = {};
    __builtin_amdgcn_s_setprio(1);
    #pragma unroll
    for (int ds = 0; ds < 4; ++ds) {
      bf16x8 kf = *(const bf16x8*)&lds_k[cur + ds*512 + lane*8];
      st = __builtin_amdgcn_mfma_f32_32x32x16_bf16(kf, qf[ds], st, 0, 0, 0);
    }
    __builtin_amdgcn_s_setprio(0);
    float p[16];
    float psum = 0.f;
    #pragma unroll
    for (int r = 0; r < 16; ++r) { p[r] = __builtin_amdgcn_exp2f(st[r]); psum += p[r]; }
    lrun += psum;

    uint32_t w0 = pkbf(p[0],p[1]),   w1 = pkbf(p[2],p[3]);
    uint32_t w2 = pkbf(p[4],p[5]),   w3 = pkbf(p[6],p[7]);
    uint32_t w4 = pkbf(p[8],p[9]),   w5 = pkbf(p[10],p[11]);
    uint32_t w6 = pkbf(p[12],p[13]), w7 = pkbf(p[14],p[15]);
    asm("v_permlane32_swap_b32 %0, %1" : "+v"(w0), "+v"(w2));
    asm("v_permlane32_swap_b32 %0, %1" : "+v"(w1), "+v"(w3));
    asm("v_permlane32_swap_b32 %0, %1" : "+v"(w4), "+v"(w6));
    asm("v_permlane32_swap_b32 %0, %1" : "+v"(w5), "+v"(w7));

    __builtin_amdgcn_s_setprio(1);
    {
      union { u32x4 u; bf16x8 b; } pu;
      u32x4 pwa = {w0, w1, w2, w3};
      pu.u = pwa;
      bf16x8 v0 = *(const bf16x8*)&lds_v[cur + 0*512 + lane*8];
      bf16x8 v1 = *(const bf16x8*)&lds_v[cur + 1*512 + lane*8];
      o0 = __builtin_amdgcn_mfma_f32_32x32x16_bf16(v0, pu.b, o0, 0, 0, 0);
      o1 = __builtin_amdgcn_mfma_f32_32x32x16_bf16(v1, pu.b, o1, 0, 0, 0);
      u32x4 pwb = {w4, w5, w6, w7};
      pu.u = pwb;
      bf16x8 v2 = *(const bf16x8*)&lds_v[cur + 2*512 + lane*8];
      bf16x8 v3 = *(const bf16x8*)&lds_v[cur + 3*512 + lane*8];
      o0 = __builtin_amdgcn_mfma_f32_32x32x16_bf16(v2, pu.b, o0, 0, 0, 0);
      o1 = __builtin_amdgcn_mfma_f32_32x32x16_bf16(v3, pu.b, o1, 0, 0, 0);
    }
    __builtin_amdgcn_s_setprio(0);

    __builtin_amdgcn_sched_barrier(0);
    __builtin_amdgcn_s_barrier();
    __builtin_amdgcn_sched_barrier(0);
  }

  lrun += __shfl_xor(lrun, 32);
  float inv = 1.f / lrun;
  bf16* aop = ao_g + ((size_t)(b_*SSEQ) + q0 + ql) * DIMN + h*HD;
  #pragma unroll
  for (int g = 0; g < 4; ++g) {
    int dbase = 8*g + 4*hi;
    bf16x4 w0 = {(bf16)(o0[4*g]*inv), (bf16)(o0[4*g+1]*inv),
                 (bf16)(o0[4*g+2]*inv), (bf16)(o0[4*g+3]*inv)};
    *(bf16x4*)&aop[dbase] = w0;
    bf16x4 w1 = {(bf16)(o1[4*g]*inv), (bf16)(o1[4*g+1]*inv),
                 (bf16)(o1[4*g+2]*inv), (bf16)(o1[4*g+3]*inv)};
    *(bf16x4*)&aop[32 + dbase] = w1;
  }
}

// ---------------------------------------------------------------------------
// Workspace layout (bytes), max footprint 126,353,408:
//   wt   [0,        8388608)   8MB  packed W (qkv 6MB / ao 2MB / gate 8MB / ffo 8MB)
//   rope [8388608,  8912896)   0.5MB
//   xb   [8912896, 17301504)   8MB  x bf16; reused as AO after attn
//   qkv  [17301504,42467328)  24MB  QF/KF/VF fragment layouts
//   P1   [17301504,50855936)  32MB  out-proj split-2 partials (qkv dead)
//   wt2  [50855936,59244544)   8MB  WlF (during fused FFN1)
//   h1b  [84410368,92798976)   8MB  rmsnorm1 bf16 out
//   ffb  [8912896, 42467328)  32MB  swiglu out (ao/qkv/P1 dead)
//   P2   [42467328,109576192) 64MB  ff-out split-4 partials (wt2/h1b dead)
//   h1f  [109576192,126353408)16MB  rmsnorm1 f32 out (long-lived resid)
extern "C" void kernel_launch(void* const* d_in, const int* in_sizes, int n_in,
                              void* d_out, int out_size, void* d_ws, size_t ws_size,
                              hipStream_t stream) {
  const float* x      = (const float*)d_in[0];
  const float* w_qkv  = (const float*)d_in[1];
  const float* w_ao   = (const float*)d_in[2];
  const float* w_gate = (const float*)d_in[3];
  const float* b_gate = (const float*)d_in[4];
  const float* w_lin  = (const float*)d_in[5];
  const float* b_lin  = (const float*)d_in[6];
  const float* w_ffo  = (const float*)d_in[7];
  const float* scale1 = (const float*)d_in[8];
  const float* scale2 = (const float*)d_in[9];
  float* out = (float*)d_out;
  (void)ws_size; (void)in_sizes; (void)n_in; (void)out_size;

  uint8_t* ws = (uint8_t*)d_ws;
  bf16*  wt_ws   = (bf16*) (ws + 0);
  float* rope_ws = (float*)(ws + 8388608);
  bf16*  xb_ws   = (bf16*) (ws + 8912896);
  bf16*  ao_ws   = (bf16*) (ws + 8912896);    // reuse XB
  bf16*  q_ws    = (bf16*) (ws + 17301504);
  bf16*  k_ws    = (bf16*) (ws + 25690112);
  bf16*  v_ws    = (bf16*) (ws + 34078720);
  float* p1_ws   = (float*)(ws + 17301504);   // 32MB, reuse QKV region
  bf16*  wt2_ws  = (bf16*) (ws + 50855936);   // 8MB  WlF
  bf16*  h1b_ws  = (bf16*) (ws + 84410368);   // 8MB
  bf16*  ffb_ws  = (bf16*) (ws + 8912896);    // 32MB, reuse XB/AO + QKV head
  float* p2_ws   = (float*)(ws + 42467328);   // 64MB, reuse wt2/h1b + gap
  float* h1f_ws  = (float*)(ws + 109576192);  // 16MB

  // 1. rope table + x cast + pack w_qkv fragments
  rope_table_kernel<<<256, 256, 0, stream>>>(rope_ws);
  cast_f32_bf16<<<4096, 256, 0, stream>>>(x, xb_ws, MROWS*DIMN/4);
  pack_wfrag<<<1536, 256, 0, stream>>>(w_qkv, wt_ws, DIMN, 3*DIMN);
  // 2. QKV gemm (rw engine) + rope epilogue -> fragment QF/KF/VF
  gemm_rw<0><<<dim3(24, 32), 256, 0, stream>>>(xb_ws, wt_ws, MROWS, 3*DIMN, DIMN,
                                               q_ws, k_ws, v_ws, rope_ws);
  // 3. attention (double-buffered KV staging, counted vmcnt)
  attn_kernel<<<dim3(16, 32), 256, 0, stream>>>(q_ws, k_ws, v_ws, ao_ws);
  // 4. out-proj (rw engine), split-K=2 -> f32 partials
  pack_wfrag<<<512, 256, 0, stream>>>(w_ao, wt_ws, DIMN, DIMN);
  gemm_rw<4><<<dim3(8, 32, 2), 256, 0, stream>>>(ao_ws, wt_ws, MROWS, DIMN, DIMN,
                                                 p1_ws, nullptr, nullptr, nullptr);
  // 5. rmsnorm1 over (p0+p1+x) -> f32 + bf16
  rmsnorm_sum_kernel<2><<<MROWS, 256, 0, stream>>>(p1_ws, x, scale1, h1f_ws, h1b_ws);
  // 6. fused FFN1 (reg-weights): sigmoid(h1b@Wg+bg) * (h1b@Wl+bl) -> bf16
  pack_wfrag<<<2048, 256, 0, stream>>>(w_gate, wt_ws, DIMN, FFN);
  pack_wfrag<<<2048, 256, 0, stream>>>(w_lin, wt2_ws, DIMN, FFN);
  gemm_ffn1_rw<<<dim3(32, 32), 256, 0, stream>>>(h1b_ws, wt_ws, wt2_ws, MROWS, FFN, DIMN,
                                                 ffb_ws, b_gate, b_lin);
  // 7. ff-out (rw engine), split-K=4 -> f32 partials
  pack_wfrag<<<2048, 256, 0, stream>>>(w_ffo, wt_ws, FFN, DIMN);
  gemm_rw<4><<<dim3(8, 32, 4), 256, 0, stream>>>(ffb_ws, wt_ws, MROWS, DIMN, FFN,
                                                 p2_ws, nullptr, nullptr, nullptr);
  // 8. rmsnorm2 over (p0+p1+p2+p3+h1f) -> output (f32)
  rmsnorm_sum_kernel<4><<<MROWS, 256, 0, stream>>>(p2_ws, h1f_ws, scale2, out, nullptr);
}